// Round 3
// baseline (7778.765 us; speedup 1.0000x reference)
//
#include <hip/hip_runtime.h>
#include <hip/hip_bf16.h>

typedef __hip_bfloat16 bf16;

#define B_  4
#define T_  2048
#define F_  128
#define D_  384
#define H_  8
#define HS_ 128
#define FF_ 512
#define NT_ (B_*T_)   /* 8192 rows */

__device__ __forceinline__ float b2f(bf16 v) { return __bfloat162float(v); }
__device__ __forceinline__ bf16  f2b(float v) { return __float2bfloat16(v); }

// dtype-adaptive input load: f32 flag chooses float* vs bf16* interpretation
__device__ __forceinline__ float ldin(const void* p, size_t i, int f32) {
    return f32 ? ((const float*)p)[i] : b2f(((const bf16*)p)[i]);
}

// ---------------------------------------------------------------------------
// Kernel 0: input-dtype detector. x is ~N(0,1): if its bytes, viewed as bf16,
// contain many huge-exponent elements, the buffer is really fp32.
// ---------------------------------------------------------------------------
__global__ void k_detect(const void* __restrict__ x, int* __restrict__ flag)
{
    if (threadIdx.x == 0 && blockIdx.x == 0) {
        const unsigned short* u = (const unsigned short*)x;
        int big = 0;
        for (int i = 0; i < 128; i++) {
            int e = (u[i] >> 7) & 0xFF;      // bf16 exponent field
            if (e >= 141) big++;             // |v| >= 2^14 : impossible for N(0,1) bf16
        }
        *flag = (big >= 8) ? 1 : 0;          // 1 = inputs are fp32
    }
}

// ---------------------------------------------------------------------------
// Kernel 1: Time2Vec + concat -> h [NT, 384] bf16
// ---------------------------------------------------------------------------
__global__ void k_t2v(const void* __restrict__ x, const void* __restrict__ wb,
                      const void* __restrict__ bb, const void* __restrict__ wa,
                      const void* __restrict__ ba, bf16* __restrict__ h,
                      const int* __restrict__ dtf)
{
    const int f32 = *dtf;
    int row = blockIdx.x;
    int f = threadIdx.x;                 // 0..127
    float xv = ldin(x, (size_t)row * F_ + f, f32);
    float prod = xv * ldin(wa, f, f32);  // K=1
    #pragma unroll
    for (int off = 32; off; off >>= 1) prod += __shfl_down(prod, off, 64);
    __shared__ float sdot[2];
    if ((threadIdx.x & 63) == 0) sdot[threadIdx.x >> 6] = prod;
    __syncthreads();
    float dot = sdot[0] + sdot[1];

    float bias = ldin(wb, f, f32) * xv + ldin(bb, f, f32);
    float sn   = sinf(dot + ldin(ba, f, f32));
    bf16* hr = h + (size_t)row * D_;
    hr[f]            = f2b(xv);
    hr[F_ + 2*f]     = f2b(bias);
    hr[F_ + 2*f + 1] = f2b(sn);
}

// ---------------------------------------------------------------------------
// Kernel 2: per-head QKV projection. grid (128, 3), block 256
// ---------------------------------------------------------------------------
__global__ void k_proj_head(const bf16* __restrict__ A,
                            const void* __restrict__ Wq, const void* __restrict__ Wk,
                            const void* __restrict__ Wv, int head,
                            bf16* __restrict__ qh, bf16* __restrict__ kh,
                            bf16* __restrict__ vh, const int* __restrict__ dtf)
{
    const int f32 = *dtf;
    int rt  = blockIdx.x;
    int mat = blockIdx.y;
    const void* W = (mat == 0 ? Wq : (mat == 1 ? Wk : Wv));
    size_t wbase = (size_t)head * D_ * HS_;
    bf16* out = (mat == 0 ? qh : (mat == 1 ? kh : vh));
    float scale = (mat == 0) ? 0.08838834764831845f : 1.0f;

    __shared__ __align__(16) float As[64][33];
    __shared__ __align__(16) float Bs[32][128];

    int tid = threadIdx.x;
    int tx = tid & 15, ty = tid >> 4;
    int row0 = rt * 64;
    float acc[4][8] = {};

    for (int k0 = 0; k0 < D_; k0 += 32) {
        for (int i = tid; i < 64 * 32; i += 256) {
            int r = i >> 5, c = i & 31;
            As[r][c] = b2f(A[(size_t)(row0 + r) * D_ + k0 + c]);
        }
        for (int i = tid; i < 32 * 128; i += 256) {
            int r = i >> 7, c = i & 127;
            Bs[r][c] = ldin(W, wbase + (size_t)(k0 + r) * HS_ + c, f32);
        }
        __syncthreads();
        #pragma unroll
        for (int kk = 0; kk < 32; kk++) {
            float av[4];
            #pragma unroll
            for (int i2 = 0; i2 < 4; i2++) av[i2] = As[ty*4 + i2][kk];
            const float4* bp4 = (const float4*)&Bs[kk][tx * 8];
            float4 b0 = bp4[0], b1 = bp4[1];
            float bv[8] = {b0.x,b0.y,b0.z,b0.w,b1.x,b1.y,b1.z,b1.w};
            #pragma unroll
            for (int i2 = 0; i2 < 4; i2++)
                #pragma unroll
                for (int j = 0; j < 8; j++) acc[i2][j] += av[i2] * bv[j];
        }
        __syncthreads();
    }
    #pragma unroll
    for (int i2 = 0; i2 < 4; i2++) {
        bf16* op = out + (size_t)(row0 + ty*4 + i2) * HS_ + tx * 8;
        #pragma unroll
        for (int j = 0; j < 8; j++) op[j] = f2b(acc[i2][j] * scale);
    }
}

// ---------------------------------------------------------------------------
// Kernel 3: flash-style attention, one head. grid (64, 4), block 256
// ---------------------------------------------------------------------------
#define TM 32
#define TN 32
__global__ void k_attn_head(const bf16* __restrict__ qh, const bf16* __restrict__ kh,
                            const bf16* __restrict__ vh, bf16* __restrict__ mo,
                            int head)
{
    int t0 = blockIdx.x * TM;
    int b  = blockIdx.y;
    const bf16* qb = qh + (size_t)b * T_ * HS_;
    const bf16* kb = kh + (size_t)b * T_ * HS_;
    const bf16* vb = vh + (size_t)b * T_ * HS_;

    __shared__ __align__(16) float Qs[TM][HS_];
    __shared__ __align__(16) float Ks[TN][HS_];
    __shared__ __align__(16) float Vs[TN][HS_];
    __shared__ float S[TM][TN];
    __shared__ float mrow[TM], lrow[TM], corr[TM];

    int tid = threadIdx.x;
    for (int i = tid; i < TM * HS_; i += 256) {
        int r = i >> 7, c = i & 127;
        Qs[r][c] = b2f(qb[(size_t)(t0 + r) * HS_ + c]);
    }
    if (tid < TM) { mrow[tid] = -1e30f; lrow[tid] = 0.f; }

    float O[16];
    #pragma unroll
    for (int j = 0; j < 16; j++) O[j] = 0.f;
    int tr = tid >> 3;                   // q-row this thread owns
    int c0 = (tid & 7) * 16;             // col base for O

    __syncthreads();

    for (int m0 = 0; m0 < T_; m0 += TN) {
        for (int i = tid; i < TN * HS_; i += 256) {
            int r = i >> 7, c = i & 127;
            Ks[r][c] = b2f(kb[(size_t)(m0 + r) * HS_ + c]);
            Vs[r][c] = b2f(vb[(size_t)(m0 + r) * HS_ + c]);
        }
        __syncthreads();

        {
            int sr = tid >> 3;
            int mj = (tid & 7) * 4;
            const float4* q4  = (const float4*)&Qs[sr][0];
            const float4* k0p = (const float4*)&Ks[mj + 0][0];
            const float4* k1p = (const float4*)&Ks[mj + 1][0];
            const float4* k2p = (const float4*)&Ks[mj + 2][0];
            const float4* k3p = (const float4*)&Ks[mj + 3][0];
            float a0 = 0, a1 = 0, a2 = 0, a3 = 0;
            #pragma unroll
            for (int ch = 0; ch < 32; ch++) {
                float4 qq = q4[ch];
                float4 x0 = k0p[ch], x1 = k1p[ch], x2 = k2p[ch], x3 = k3p[ch];
                a0 += qq.x*x0.x + qq.y*x0.y + qq.z*x0.z + qq.w*x0.w;
                a1 += qq.x*x1.x + qq.y*x1.y + qq.z*x1.z + qq.w*x1.w;
                a2 += qq.x*x2.x + qq.y*x2.y + qq.z*x2.z + qq.w*x2.w;
                a3 += qq.x*x3.x + qq.y*x3.y + qq.z*x3.z + qq.w*x3.w;
            }
            S[sr][mj+0] = a0; S[sr][mj+1] = a1; S[sr][mj+2] = a2; S[sr][mj+3] = a3;
        }
        __syncthreads();

        if (tid < TM) {
            int r = tid;
            float mold = mrow[r];
            float mx = mold;
            #pragma unroll
            for (int m = 0; m < TN; m++) mx = fmaxf(mx, S[r][m]);
            float cr = __expf(mold - mx);
            float sum = 0.f;
            #pragma unroll
            for (int m = 0; m < TN; m++) {
                float p = __expf(S[r][m] - mx);
                S[r][m] = p;
                sum += p;
            }
            lrow[r] = lrow[r] * cr + sum;
            mrow[r] = mx;
            corr[r] = cr;
        }
        __syncthreads();

        float cr = corr[tr];
        #pragma unroll
        for (int j = 0; j < 16; j++) O[j] *= cr;
        #pragma unroll 4
        for (int mm = 0; mm < TN; mm++) {
            float p = S[tr][mm];
            const float4* v4 = (const float4*)&Vs[mm][c0];
            #pragma unroll
            for (int j4 = 0; j4 < 4; j4++) {
                float4 vv = v4[j4];
                O[j4*4+0] += p * vv.x; O[j4*4+1] += p * vv.y;
                O[j4*4+2] += p * vv.z; O[j4*4+3] += p * vv.w;
            }
        }
        __syncthreads();
    }

    float inv = 1.f / lrow[tr];
    int t = t0 + tr;
    bf16* mor = mo + (((size_t)(b * T_ + t)) * H_ + head) * HS_ + c0;
    #pragma unroll
    for (int j = 0; j < 16; j++) mor[j] = f2b(O[j] * inv);
}

// ---------------------------------------------------------------------------
// Kernel 4: GEMM  C[8192 x N] = A[8192 x Kd](bf16 ws) * W[Kd x N](input) + bias
// ---------------------------------------------------------------------------
template<bool RELU>
__global__ void k_gemm(const bf16* __restrict__ A, const void* __restrict__ W,
                       const void* __restrict__ bias, bf16* __restrict__ C,
                       int Kd, int N, const int* __restrict__ dtf)
{
    const int f32 = *dtf;
    int rt = blockIdx.x, nt = blockIdx.y;
    __shared__ __align__(16) float As[64][33];
    __shared__ __align__(16) float Bs[32][128];

    int tid = threadIdx.x;
    int tx = tid & 15, ty = tid >> 4;
    int row0 = rt * 64, col0 = nt * 128;
    float acc[4][8] = {};

    for (int k0 = 0; k0 < Kd; k0 += 32) {
        for (int i = tid; i < 64 * 32; i += 256) {
            int r = i >> 5, c = i & 31;
            As[r][c] = b2f(A[(size_t)(row0 + r) * Kd + k0 + c]);
        }
        for (int i = tid; i < 32 * 128; i += 256) {
            int r = i >> 7, c = i & 127;
            Bs[r][c] = ldin(W, (size_t)(k0 + r) * N + col0 + c, f32);
        }
        __syncthreads();
        #pragma unroll
        for (int kk = 0; kk < 32; kk++) {
            float av[4];
            #pragma unroll
            for (int i2 = 0; i2 < 4; i2++) av[i2] = As[ty*4 + i2][kk];
            const float4* bp4 = (const float4*)&Bs[kk][tx * 8];
            float4 b0 = bp4[0], b1 = bp4[1];
            float bv[8] = {b0.x,b0.y,b0.z,b0.w,b1.x,b1.y,b1.z,b1.w};
            #pragma unroll
            for (int i2 = 0; i2 < 4; i2++)
                #pragma unroll
                for (int j = 0; j < 8; j++) acc[i2][j] += av[i2] * bv[j];
        }
        __syncthreads();
    }
    #pragma unroll
    for (int i2 = 0; i2 < 4; i2++) {
        bf16* cp = C + (size_t)(row0 + ty*4 + i2) * N + col0 + tx * 8;
        #pragma unroll
        for (int j = 0; j < 8; j++) {
            float val = acc[i2][j] + ldin(bias, col0 + tx*8 + j, f32);
            if (RELU) val = fmaxf(val, 0.f);
            cp[j] = f2b(val);
        }
    }
}

// ---------------------------------------------------------------------------
// Kernel 5: residual + LayerNorm. FINAL=true writes d_out (dtype per flag);
// else writes bf16 ws. Safe in-place (out==in1): reads precede sync barriers.
// ---------------------------------------------------------------------------
template<bool FINAL>
__global__ void k_ln(const bf16* __restrict__ in1, const bf16* __restrict__ in2,
                     const void* __restrict__ g, const void* __restrict__ be,
                     void* __restrict__ out, const int* __restrict__ dtf)
{
    const int f32 = *dtf;
    int row = blockIdx.x;
    int tid = threadIdx.x;
    size_t base = (size_t)row * D_;
    int c0 = tid, c1 = tid + 128, c2 = tid + 256;
    float x0 = b2f(in1[base + c0]) + b2f(in2[base + c0]);
    float x1 = b2f(in1[base + c1]) + b2f(in2[base + c1]);
    float x2 = b2f(in1[base + c2]) + b2f(in2[base + c2]);

    __shared__ float sb1[2], sb2[2];
    float s = x0 + x1 + x2;
    #pragma unroll
    for (int off = 32; off; off >>= 1) s += __shfl_down(s, off, 64);
    if ((tid & 63) == 0) sb1[tid >> 6] = s;
    __syncthreads();
    float m = (sb1[0] + sb1[1]) * (1.f / D_);

    float d0 = x0 - m, d1 = x1 - m, d2 = x2 - m;
    float sq = d0*d0 + d1*d1 + d2*d2;
    #pragma unroll
    for (int off = 32; off; off >>= 1) sq += __shfl_down(sq, off, 64);
    if ((tid & 63) == 0) sb2[tid >> 6] = sq;
    __syncthreads();
    float rstd = rsqrtf((sb2[0] + sb2[1]) * (1.f / D_) + 1e-6f);

    float y0 = ldin(g, c0, f32) * d0 * rstd + ldin(be, c0, f32);
    float y1 = ldin(g, c1, f32) * d1 * rstd + ldin(be, c1, f32);
    float y2 = ldin(g, c2, f32) * d2 * rstd + ldin(be, c2, f32);
    if (FINAL && f32) {
        float* o = (float*)out;
        o[base + c0] = y0; o[base + c1] = y1; o[base + c2] = y2;
    } else {
        bf16* o = (bf16*)out;
        o[base + c0] = f2b(y0); o[base + c1] = f2b(y1); o[base + c2] = f2b(y2);
    }
}

// ---------------------------------------------------------------------------
// Workspace (bf16 elems): h[3,145,728] | qh/kh/vh[1,048,576 ea] | mo[8,388,608]
// aliases: a=qh (qkv dead), h1=h (in-place), f=qh (mo head dead), f2=mo+2,097,152
// flag int at byte offset 29,360,128. Total ~28 MB.
// ---------------------------------------------------------------------------
extern "C" void kernel_launch(void* const* d_in, const int* in_sizes, int n_in,
                              void* d_out, int out_size, void* d_ws, size_t ws_size,
                              hipStream_t stream)
{
    const void* x     = d_in[0];
    const void* wb    = d_in[1];
    const void* bb    = d_in[2];
    const void* wa    = d_in[3];
    const void* ba    = d_in[4];
    const void* Wq    = d_in[5];
    const void* Wk    = d_in[6];
    const void* Wv    = d_in[7];
    const void* Wp    = d_in[8];
    const void* bp    = d_in[9];
    const void* ln1_g = d_in[10];
    const void* ln1_b = d_in[11];
    const void* W1    = d_in[12];
    const void* b1    = d_in[13];
    const void* W2    = d_in[14];
    const void* b2    = d_in[15];
    const void* ln2_g = d_in[16];
    const void* ln2_b = d_in[17];

    bf16* ws = (bf16*)d_ws;
    bf16* h  = ws;
    bf16* qh = h  + (size_t)NT_ * D_;
    bf16* kh = qh + (size_t)NT_ * HS_;
    bf16* vh = kh + (size_t)NT_ * HS_;
    bf16* mo = vh + (size_t)NT_ * HS_;
    bf16* a  = qh;
    bf16* h1 = h;
    bf16* f  = qh;
    bf16* f2 = mo + 2097152;
    int* flag = (int*)(mo + (size_t)NT_ * H_ * HS_);

    k_detect<<<1, 64, 0, stream>>>(x, flag);

    k_t2v<<<NT_, 128, 0, stream>>>(x, wb, bb, wa, ba, h, flag);

    for (int head = 0; head < H_; head++) {
        dim3 gq(NT_ / 64, 3);
        k_proj_head<<<gq, 256, 0, stream>>>(h, Wq, Wk, Wv, head, qh, kh, vh, flag);
        dim3 gatt(T_ / TM, B_);
        k_attn_head<<<gatt, 256, 0, stream>>>(qh, kh, vh, mo, head);
    }

    dim3 gp(NT_ / 64, D_ / 128);
    k_gemm<false><<<gp, 256, 0, stream>>>(mo, Wp, bp, a, H_ * HS_, D_, flag);

    k_ln<false><<<NT_, 128, 0, stream>>>(h, a, ln1_g, ln1_b, h1, flag);

    dim3 g1(NT_ / 64, FF_ / 128);
    k_gemm<true><<<g1, 256, 0, stream>>>(h1, W1, b1, f, D_, FF_, flag);

    dim3 g2(NT_ / 64, D_ / 128);
    k_gemm<false><<<g2, 256, 0, stream>>>(f, W2, b2, f2, FF_, D_, flag);

    k_ln<true><<<NT_, 128, 0, stream>>>(h1, f2, ln2_g, ln2_b, d_out, flag);
}

// Round 4
// 1275.099 us; speedup vs baseline: 6.1005x; 6.1005x over previous
//
#include <hip/hip_runtime.h>
#include <hip/hip_bf16.h>

typedef __hip_bfloat16 bf16;
typedef __attribute__((ext_vector_type(8))) short short8;
typedef __attribute__((ext_vector_type(4))) float floatx4;

#define B_  4
#define T_  2048
#define F_  128
#define D_  384
#define H_  8
#define HS_ 128
#define FF_ 512
#define NT_ (B_*T_)   /* 8192 rows */

__device__ __forceinline__ float b2f(bf16 v) { return __bfloat162float(v); }
__device__ __forceinline__ bf16  f2b(float v) { return __float2bfloat16(v); }
__device__ __forceinline__ unsigned short f2bu(float f) {
    bf16 b = __float2bfloat16(f);
    union { bf16 h; unsigned short u; } cv; cv.h = b; return cv.u;
}

// dtype-adaptive input load: f32 flag chooses float* vs bf16* interpretation
__device__ __forceinline__ float ldin(const void* p, size_t i, int f32) {
    return f32 ? ((const float*)p)[i] : b2f(((const bf16*)p)[i]);
}

// ---------------------------------------------------------------------------
// Kernel 0: input-dtype detector (x ~ N(0,1); fp32 bytes read as bf16 show
// huge exponents).
// ---------------------------------------------------------------------------
__global__ void k_detect(const void* __restrict__ x, int* __restrict__ flag)
{
    if (threadIdx.x == 0 && blockIdx.x == 0) {
        const unsigned short* u = (const unsigned short*)x;
        int big = 0;
        for (int i = 0; i < 128; i++) {
            int e = (u[i] >> 7) & 0xFF;
            if (e >= 141) big++;
        }
        *flag = (big >= 8) ? 1 : 0;
    }
}

// ---------------------------------------------------------------------------
// Kernel 1: Time2Vec + concat -> h [NT, 384] bf16
// ---------------------------------------------------------------------------
__global__ void k_t2v(const void* __restrict__ x, const void* __restrict__ wb,
                      const void* __restrict__ bb, const void* __restrict__ wa,
                      const void* __restrict__ ba, bf16* __restrict__ h,
                      const int* __restrict__ dtf)
{
    const int f32 = *dtf;
    int row = blockIdx.x;
    int f = threadIdx.x;                 // 0..127
    float xv = ldin(x, (size_t)row * F_ + f, f32);
    float prod = xv * ldin(wa, f, f32);  // K=1
    #pragma unroll
    for (int off = 32; off; off >>= 1) prod += __shfl_down(prod, off, 64);
    __shared__ float sdot[2];
    if ((threadIdx.x & 63) == 0) sdot[threadIdx.x >> 6] = prod;
    __syncthreads();
    float dot = sdot[0] + sdot[1];

    float bias = ldin(wb, f, f32) * xv + ldin(bb, f, f32);
    float sn   = sinf(dot + ldin(ba, f, f32));
    bf16* hr = h + (size_t)row * D_;
    hr[f]            = f2b(xv);
    hr[F_ + 2*f]     = f2b(bias);
    hr[F_ + 2*f + 1] = f2b(sn);
}

// ---------------------------------------------------------------------------
// Kernel 2: QKV projection, 4 heads per launch. grid (128, 4, 3), block 256
// out layout per buffer: [hh, B*T, HS] (hh = head within round)
// ---------------------------------------------------------------------------
__global__ void k_proj4(const bf16* __restrict__ A,
                        const void* __restrict__ Wq, const void* __restrict__ Wk,
                        const void* __restrict__ Wv, int round,
                        bf16* __restrict__ q4, bf16* __restrict__ k4,
                        bf16* __restrict__ v4, const int* __restrict__ dtf)
{
    const int f32 = *dtf;
    int rt  = blockIdx.x;
    int hh  = blockIdx.y;                // head within round (0..3)
    int mat = blockIdx.z;
    int head = round * 4 + hh;
    const void* W = (mat == 0 ? Wq : (mat == 1 ? Wk : Wv));
    size_t wbase = (size_t)head * D_ * HS_;
    bf16* out = (mat == 0 ? q4 : (mat == 1 ? k4 : v4)) + (size_t)hh * NT_ * HS_;
    float scale = (mat == 0) ? 0.08838834764831845f : 1.0f;

    __shared__ __align__(16) float As[64][33];
    __shared__ __align__(16) float Bs[32][128];

    int tid = threadIdx.x;
    int tx = tid & 15, ty = tid >> 4;
    int row0 = rt * 64;
    float acc[4][8] = {};

    for (int k0 = 0; k0 < D_; k0 += 32) {
        for (int i = tid; i < 64 * 32; i += 256) {
            int r = i >> 5, c = i & 31;
            As[r][c] = b2f(A[(size_t)(row0 + r) * D_ + k0 + c]);
        }
        for (int i = tid; i < 32 * 128; i += 256) {
            int r = i >> 7, c = i & 127;
            Bs[r][c] = ldin(W, wbase + (size_t)(k0 + r) * HS_ + c, f32);
        }
        __syncthreads();
        #pragma unroll
        for (int kk = 0; kk < 32; kk++) {
            float av[4];
            #pragma unroll
            for (int i2 = 0; i2 < 4; i2++) av[i2] = As[ty*4 + i2][kk];
            const float4* bp4 = (const float4*)&Bs[kk][tx * 8];
            float4 b0 = bp4[0], b1 = bp4[1];
            float bv[8] = {b0.x,b0.y,b0.z,b0.w,b1.x,b1.y,b1.z,b1.w};
            #pragma unroll
            for (int i2 = 0; i2 < 4; i2++)
                #pragma unroll
                for (int j = 0; j < 8; j++) acc[i2][j] += av[i2] * bv[j];
        }
        __syncthreads();
    }
    #pragma unroll
    for (int i2 = 0; i2 < 4; i2++) {
        bf16* op = out + (size_t)(row0 + ty*4 + i2) * HS_ + tx * 8;
        #pragma unroll
        for (int j = 0; j < 8; j++) op[j] = f2b(acc[i2][j] * scale);
    }
}

// ---------------------------------------------------------------------------
// Kernel 3: MFMA flash attention, 4 heads/launch.
// grid (T/64 = 32, B*4 = 16), block 256 (4 waves; wave w owns q-rows w*16..+15)
// q4/k4/v4: [hh, B*T, HS] bf16 -> mo [B,T,H,HS] bf16
//
// mfma_f32_16x16x32_bf16 layouts (m89/m120-verified):
//   A-frag: lane holds A[m=lane&15][k=(lane>>4)*8+j]  (8 contiguous bf16)
//   B-frag: lane holds B[k=(lane>>4)*8+j][n=lane&15]
//   C/D   : lane holds D[row=4*(lane>>4)+reg][col=lane&15]
// QK^T: A=Q rows, B=K^T -> lane reads K row (lane&15) contiguous. PV: B=V ->
// lane needs a V column -> V staged transposed (Vt[d][kv]).
// ---------------------------------------------------------------------------
#define ATM 64      /* q rows per block */
#define ATN 64      /* kv per iteration */
__global__ __launch_bounds__(256) void
k_attn_mfma(const bf16* __restrict__ q4, const bf16* __restrict__ k4,
            const bf16* __restrict__ v4, bf16* __restrict__ mo, int round)
{
    __shared__ __align__(16) bf16 Qs[64][136];   // stride 136 bf16 (pad +8)
    __shared__ __align__(16) bf16 Ks[64][136];
    __shared__ __align__(16) bf16 Vt[128][72];   // transposed V, stride 72
    __shared__ __align__(16) float Sw[4][16][68];// per-wave S (reused as P bf16)

    const int tid  = threadIdx.x;
    const int wave = tid >> 6;
    const int lane = tid & 63;
    const int r    = lane & 15;
    const int g    = lane >> 4;

    const int by = blockIdx.y;
    const int hh = by >> 2, b = by & 3;
    const int t0 = blockIdx.x * ATM;
    const int head = round * 4 + hh;

    const bf16* qb = q4 + ((size_t)(hh * B_ + b) * T_ + t0) * HS_;
    const bf16* kb = k4 + (size_t)(hh * B_ + b) * T_ * HS_;
    const bf16* vb = v4 + (size_t)(hh * B_ + b) * T_ * HS_;

    // ---- stage Q (64 x 128) ----
    for (int i = tid; i < 1024; i += 256) {
        int row = i >> 4, c8 = i & 15;
        *(uint4*)&Qs[row][c8 * 8] =
            *(const uint4*)(qb + (size_t)row * HS_ + c8 * 8);
    }
    __syncthreads();

    // Q A-frags (loop-invariant): 4 k-steps of K-dim 128
    short8 qfrag[4];
    #pragma unroll
    for (int ks = 0; ks < 4; ks++)
        qfrag[ks] = *(const short8*)&Qs[wave * 16 + r][ks * 32 + g * 8];

    floatx4 O[8];
    #pragma unroll
    for (int dt = 0; dt < 8; dt++) O[dt] = (floatx4){0.f, 0.f, 0.f, 0.f};
    float m_run = -1e30f, l_run = 0.f;

    bf16* pbase = (bf16*)&Sw[wave][0][0];   // P view: row stride 136 bf16

    for (int m0 = 0; m0 < T_; m0 += ATN) {
        __syncthreads();                     // protect Ks/Vt from prior iter reads
        // ---- stage K tile (64 x 128) ----
        for (int i = tid; i < 1024; i += 256) {
            int row = i >> 4, c8 = i & 15;
            *(uint4*)&Ks[row][c8 * 8] =
                *(const uint4*)(kb + (size_t)(m0 + row) * HS_ + c8 * 8);
        }
        // ---- stage V transposed (kv 64 x d 128 -> Vt[d][kv]) ----
        for (int i = tid; i < 1024; i += 256) {
            int kv = i & 63, c8 = i >> 6;
            uint4 raw = *(const uint4*)(vb + (size_t)(m0 + kv) * HS_ + c8 * 8);
            const bf16* e = (const bf16*)&raw;
            #pragma unroll
            for (int j = 0; j < 8; j++) Vt[c8 * 8 + j][kv] = e[j];
        }
        __syncthreads();

        // ---- S = Q K^T (16 x 64 per wave) ----
        #pragma unroll
        for (int nt = 0; nt < 4; nt++) {
            floatx4 acc = (floatx4){0.f, 0.f, 0.f, 0.f};
            #pragma unroll
            for (int ks = 0; ks < 4; ks++) {
                short8 kf = *(const short8*)&Ks[nt * 16 + r][ks * 32 + g * 8];
                acc = __builtin_amdgcn_mfma_f32_16x16x32_bf16(qfrag[ks], kf, acc, 0, 0, 0);
            }
            #pragma unroll
            for (int reg = 0; reg < 4; reg++)
                Sw[wave][4 * g + reg][nt * 16 + r] = acc[reg];
        }
        asm volatile("s_waitcnt lgkmcnt(0)" ::: "memory");

        // ---- online softmax: lane owns row r, cols 16g..16g+15 ----
        float sv[16];
        #pragma unroll
        for (int q4i = 0; q4i < 4; q4i++) {
            float4 t = *(const float4*)&Sw[wave][r][16 * g + 4 * q4i];
            sv[4*q4i+0] = t.x; sv[4*q4i+1] = t.y; sv[4*q4i+2] = t.z; sv[4*q4i+3] = t.w;
        }
        float mx = m_run;
        #pragma unroll
        for (int j = 0; j < 16; j++) mx = fmaxf(mx, sv[j]);
        mx = fmaxf(mx, __shfl_xor(mx, 16));
        mx = fmaxf(mx, __shfl_xor(mx, 32));
        float cr = __expf(m_run - mx);
        float tsum = 0.f;
        #pragma unroll
        for (int j = 0; j < 16; j++) { sv[j] = __expf(sv[j] - mx); tsum += sv[j]; }
        tsum += __shfl_xor(tsum, 16);
        tsum += __shfl_xor(tsum, 32);
        l_run = l_run * cr + tsum;
        m_run = mx;

        // write P (bf16) over Sw: row r, k-cols 16g..16g+15
        short8 p0, p1;
        #pragma unroll
        for (int j = 0; j < 8; j++) {
            p0[j] = (short)f2bu(sv[j]);
            p1[j] = (short)f2bu(sv[8 + j]);
        }
        *(short8*)(pbase + r * 136 + 16 * g)     = p0;
        *(short8*)(pbase + r * 136 + 16 * g + 8) = p1;
        asm volatile("s_waitcnt lgkmcnt(0)" ::: "memory");

        // ---- rescale O by per-row cr ----
        float crg[4];
        #pragma unroll
        for (int reg = 0; reg < 4; reg++) crg[reg] = __shfl(cr, 4 * g + reg);
        #pragma unroll
        for (int dt = 0; dt < 8; dt++) {
            O[dt][0] *= crg[0]; O[dt][1] *= crg[1];
            O[dt][2] *= crg[2]; O[dt][3] *= crg[3];
        }

        // ---- O += P V ----
        short8 pf0 = *(const short8*)(pbase + r * 136 + 8 * g);
        short8 pf1 = *(const short8*)(pbase + r * 136 + 32 + 8 * g);
        #pragma unroll
        for (int dt = 0; dt < 8; dt++) {
            short8 vf0 = *(const short8*)&Vt[dt * 16 + r][8 * g];
            O[dt] = __builtin_amdgcn_mfma_f32_16x16x32_bf16(pf0, vf0, O[dt], 0, 0, 0);
            short8 vf1 = *(const short8*)&Vt[dt * 16 + r][32 + 8 * g];
            O[dt] = __builtin_amdgcn_mfma_f32_16x16x32_bf16(pf1, vf1, O[dt], 0, 0, 0);
        }
    }

    // ---- epilogue: O / l, write mo [B,T,H,HS] ----
    float linv[4];
    #pragma unroll
    for (int reg = 0; reg < 4; reg++) linv[reg] = 1.f / __shfl(l_run, 4 * g + reg);
    #pragma unroll
    for (int dt = 0; dt < 8; dt++) {
        #pragma unroll
        for (int reg = 0; reg < 4; reg++) {
            int t = t0 + wave * 16 + 4 * g + reg;
            mo[(((size_t)(b * T_ + t)) * H_ + head) * HS_ + dt * 16 + r] =
                f2b(O[dt][reg] * linv[reg]);
        }
    }
}

// ---------------------------------------------------------------------------
// Kernel 4: GEMM  C[8192 x N] = A[8192 x Kd](bf16 ws) * W[Kd x N](input) + bias
// ---------------------------------------------------------------------------
template<bool RELU>
__global__ void k_gemm(const bf16* __restrict__ A, const void* __restrict__ W,
                       const void* __restrict__ bias, bf16* __restrict__ C,
                       int Kd, int N, const int* __restrict__ dtf)
{
    const int f32 = *dtf;
    int rt = blockIdx.x, nt = blockIdx.y;
    __shared__ __align__(16) float As[64][33];
    __shared__ __align__(16) float Bs[32][128];

    int tid = threadIdx.x;
    int tx = tid & 15, ty = tid >> 4;
    int row0 = rt * 64, col0 = nt * 128;
    float acc[4][8] = {};

    for (int k0 = 0; k0 < Kd; k0 += 32) {
        for (int i = tid; i < 64 * 32; i += 256) {
            int r = i >> 5, c = i & 31;
            As[r][c] = b2f(A[(size_t)(row0 + r) * Kd + k0 + c]);
        }
        for (int i = tid; i < 32 * 128; i += 256) {
            int r = i >> 7, c = i & 127;
            Bs[r][c] = ldin(W, (size_t)(k0 + r) * N + col0 + c, f32);
        }
        __syncthreads();
        #pragma unroll
        for (int kk = 0; kk < 32; kk++) {
            float av[4];
            #pragma unroll
            for (int i2 = 0; i2 < 4; i2++) av[i2] = As[ty*4 + i2][kk];
            const float4* bp4 = (const float4*)&Bs[kk][tx * 8];
            float4 b0 = bp4[0], b1 = bp4[1];
            float bv[8] = {b0.x,b0.y,b0.z,b0.w,b1.x,b1.y,b1.z,b1.w};
            #pragma unroll
            for (int i2 = 0; i2 < 4; i2++)
                #pragma unroll
                for (int j = 0; j < 8; j++) acc[i2][j] += av[i2] * bv[j];
        }
        __syncthreads();
    }
    #pragma unroll
    for (int i2 = 0; i2 < 4; i2++) {
        bf16* cp = C + (size_t)(row0 + ty*4 + i2) * N + col0 + tx * 8;
        #pragma unroll
        for (int j = 0; j < 8; j++) {
            float val = acc[i2][j] + ldin(bias, col0 + tx*8 + j, f32);
            if (RELU) val = fmaxf(val, 0.f);
            cp[j] = f2b(val);
        }
    }
}

// ---------------------------------------------------------------------------
// Kernel 5: residual + LayerNorm. FINAL=true writes d_out (dtype per flag).
// Safe in-place (out==in1): all reads precede the reduction barriers.
// ---------------------------------------------------------------------------
template<bool FINAL>
__global__ void k_ln(const bf16* __restrict__ in1, const bf16* __restrict__ in2,
                     const void* __restrict__ g, const void* __restrict__ be,
                     void* __restrict__ out, const int* __restrict__ dtf)
{
    const int f32 = *dtf;
    int row = blockIdx.x;
    int tid = threadIdx.x;
    size_t base = (size_t)row * D_;
    int c0 = tid, c1 = tid + 128, c2 = tid + 256;
    float x0 = b2f(in1[base + c0]) + b2f(in2[base + c0]);
    float x1 = b2f(in1[base + c1]) + b2f(in2[base + c1]);
    float x2 = b2f(in1[base + c2]) + b2f(in2[base + c2]);

    __shared__ float sb1[2], sb2[2];
    float s = x0 + x1 + x2;
    #pragma unroll
    for (int off = 32; off; off >>= 1) s += __shfl_down(s, off, 64);
    if ((tid & 63) == 0) sb1[tid >> 6] = s;
    __syncthreads();
    float m = (sb1[0] + sb1[1]) * (1.f / D_);

    float d0 = x0 - m, d1 = x1 - m, d2 = x2 - m;
    float sq = d0*d0 + d1*d1 + d2*d2;
    #pragma unroll
    for (int off = 32; off; off >>= 1) sq += __shfl_down(sq, off, 64);
    if ((tid & 63) == 0) sb2[tid >> 6] = sq;
    __syncthreads();
    float rstd = rsqrtf((sb2[0] + sb2[1]) * (1.f / D_) + 1e-6f);

    float y0 = ldin(g, c0, f32) * d0 * rstd + ldin(be, c0, f32);
    float y1 = ldin(g, c1, f32) * d1 * rstd + ldin(be, c1, f32);
    float y2 = ldin(g, c2, f32) * d2 * rstd + ldin(be, c2, f32);
    if (FINAL && f32) {
        float* o = (float*)out;
        o[base + c0] = y0; o[base + c1] = y1; o[base + c2] = y2;
    } else {
        bf16* o = (bf16*)out;
        o[base + c0] = f2b(y0); o[base + c1] = f2b(y1); o[base + c2] = f2b(y2);
    }
}

// ---------------------------------------------------------------------------
// Workspace (bf16 elems), peak ~46 MB:
//   h   [NT*D   = 3,145,728] @ 0
//   q4  [4*NT*HS= 4,194,304] @  3,145,728
//   k4  [4,194,304]          @  7,340,032
//   v4  [4,194,304]          @ 11,534,336
//   mo  [NT*H*HS= 8,388,608] @ 15,728,640
// aliases: a=q4 (qkv dead post-attn), h1=h (in-place), f=k4 (4,194,304 exact),
//          f2=v4. flag int @ bf16-offset 24,117,248.
// ---------------------------------------------------------------------------
extern "C" void kernel_launch(void* const* d_in, const int* in_sizes, int n_in,
                              void* d_out, int out_size, void* d_ws, size_t ws_size,
                              hipStream_t stream)
{
    const void* x     = d_in[0];
    const void* wb    = d_in[1];
    const void* bb    = d_in[2];
    const void* wa    = d_in[3];
    const void* ba    = d_in[4];
    const void* Wq    = d_in[5];
    const void* Wk    = d_in[6];
    const void* Wv    = d_in[7];
    const void* Wp    = d_in[8];
    const void* bp    = d_in[9];
    const void* ln1_g = d_in[10];
    const void* ln1_b = d_in[11];
    const void* W1    = d_in[12];
    const void* b1    = d_in[13];
    const void* W2    = d_in[14];
    const void* b2    = d_in[15];
    const void* ln2_g = d_in[16];
    const void* ln2_b = d_in[17];

    bf16* ws = (bf16*)d_ws;
    bf16* h  = ws;
    bf16* q4 = h  + (size_t)NT_ * D_;
    bf16* k4 = q4 + (size_t)4 * NT_ * HS_;
    bf16* v4 = k4 + (size_t)4 * NT_ * HS_;
    bf16* mo = v4 + (size_t)4 * NT_ * HS_;
    bf16* a  = q4;
    bf16* h1 = h;
    bf16* f  = k4;
    bf16* f2 = v4;
    int* flag = (int*)(mo + (size_t)NT_ * H_ * HS_);

    k_detect<<<1, 64, 0, stream>>>(x, flag);

    k_t2v<<<NT_, 128, 0, stream>>>(x, wb, bb, wa, ba, h, flag);

    for (int round = 0; round < 2; round++) {
        dim3 gq(NT_ / 64, 4, 3);
        k_proj4<<<gq, 256, 0, stream>>>(h, Wq, Wk, Wv, round, q4, k4, v4, flag);
        dim3 gatt(T_ / ATM, B_ * 4);
        k_attn_mfma<<<gatt, 256, 0, stream>>>(q4, k4, v4, mo, round);
    }

    dim3 gp(NT_ / 64, D_ / 128);
    k_gemm<false><<<gp, 256, 0, stream>>>(mo, Wp, bp, a, H_ * HS_, D_, flag);

    k_ln<false><<<NT_, 128, 0, stream>>>(h, a, ln1_g, ln1_b, h1, flag);

    dim3 g1(NT_ / 64, FF_ / 128);
    k_gemm<true><<<g1, 256, 0, stream>>>(h1, W1, b1, f, D_, FF_, flag);

    dim3 g2(NT_ / 64, D_ / 128);
    k_gemm<false><<<g2, 256, 0, stream>>>(f, W2, b2, f2, FF_, D_, flag);

    k_ln<true><<<NT_, 128, 0, stream>>>(h1, f2, ln2_g, ln2_b, d_out, flag);
}

// Round 5
// 480.277 us; speedup vs baseline: 16.1964x; 2.6549x over previous
//
#include <hip/hip_runtime.h>
#include <hip/hip_bf16.h>

typedef __hip_bfloat16 bf16;
typedef __attribute__((ext_vector_type(8))) short short8;
typedef __attribute__((ext_vector_type(4))) float floatx4;

#define B_  4
#define T_  2048
#define F_  128
#define D_  384
#define H_  8
#define HS_ 128
#define FF_ 512
#define NT_ (B_*T_)   /* 8192 rows */
#define QS_ 1536      /* qkv GEMM row stride: 3 mats x 4 heads x 128 */

__device__ __forceinline__ float b2f(bf16 v) { return __bfloat162float(v); }
__device__ __forceinline__ bf16  f2b(float v) { return __float2bfloat16(v); }
__device__ __forceinline__ unsigned short f2bu(float f) {
    bf16 b = __float2bfloat16(f);
    union { bf16 h; unsigned short u; } cv; cv.h = b; return cv.u;
}

// dtype-adaptive input load: f32 flag chooses float* vs bf16* interpretation
__device__ __forceinline__ float ldin(const void* p, size_t i, int f32) {
    return f32 ? ((const float*)p)[i] : b2f(((const bf16*)p)[i]);
}

// ---------------------------------------------------------------------------
// Kernel 0: input-dtype detector (x ~ N(0,1); fp32 bytes read as bf16 show
// huge exponents).
// ---------------------------------------------------------------------------
__global__ void k_detect(const void* __restrict__ x, int* __restrict__ flag)
{
    if (threadIdx.x == 0 && blockIdx.x == 0) {
        const unsigned short* u = (const unsigned short*)x;
        int big = 0;
        for (int i = 0; i < 128; i++) {
            int e = (u[i] >> 7) & 0xFF;
            if (e >= 141) big++;
        }
        *flag = (big >= 8) ? 1 : 0;
    }
}

// ---------------------------------------------------------------------------
// Weight pack kernels: input (fp32 or bf16) -> transposed bf16 Wt[N][K]
// ---------------------------------------------------------------------------
// wqkv[round][n][k], n = mat*512 + hh*128 + ch, head = round*4+hh, k in [0,384)
__global__ void k_pack_qkv(const void* __restrict__ Wq, const void* __restrict__ Wk,
                           const void* __restrict__ Wv, bf16* __restrict__ dst,
                           const int* __restrict__ dtf)
{
    const int f32 = *dtf;
    int idx = blockIdx.x * 256 + threadIdx.x;          // < 2*1536*384
    int k   = idx % D_;
    int n   = (idx / D_) % QS_;
    int rnd = idx / (D_ * QS_);
    int mat = n >> 9, w = n & 511, hh = w >> 7, ch = w & 127;
    int head = rnd * 4 + hh;
    const void* W = (mat == 0 ? Wq : (mat == 1 ? Wk : Wv));
    float v = ldin(W, (size_t)head * D_ * HS_ + (size_t)k * HS_ + ch, f32);
    if (mat == 0) v *= 0.08838834764831845f;           // q / sqrt(HS)
    dst[idx] = f2b(v);
}

// wp_t[o][h*128+i] = Wp[h][i][o]   (K=1024, N=384)
__global__ void k_pack_wp(const void* __restrict__ Wp, bf16* __restrict__ dst,
                          const int* __restrict__ dtf)
{
    const int f32 = *dtf;
    int idx = blockIdx.x * 256 + threadIdx.x;          // < 384*1024
    int c = idx & 1023, o = idx >> 10;
    int h = c >> 7, i = c & 127;
    dst[idx] = f2b(ldin(Wp, (size_t)(h * HS_ + i) * D_ + o, f32));
}

// w1_t[f][d] = W1[d][f]  (K=384, N=512)
__global__ void k_pack_w1(const void* __restrict__ W1, bf16* __restrict__ dst,
                          const int* __restrict__ dtf)
{
    const int f32 = *dtf;
    int idx = blockIdx.x * 256 + threadIdx.x;          // < 512*384
    int d = idx % D_, f = idx / D_;
    dst[idx] = f2b(ldin(W1, (size_t)d * FF_ + f, f32));
}

// w2_t[d][f] = W2[f][d]  (K=512, N=384)
__global__ void k_pack_w2(const void* __restrict__ W2, bf16* __restrict__ dst,
                          const int* __restrict__ dtf)
{
    const int f32 = *dtf;
    int idx = blockIdx.x * 256 + threadIdx.x;          // < 384*512
    int f = idx % FF_, d = idx / FF_;
    dst[idx] = f2b(ldin(W2, (size_t)f * D_ + d, f32));
}

// bias pack: [0,1536) zeros | [1536,1920) bp | [1920,2432) b1 | [2432,2816) b2
__global__ void k_pack_bias(const void* __restrict__ bp, const void* __restrict__ b1,
                            const void* __restrict__ b2, bf16* __restrict__ dst,
                            const int* __restrict__ dtf)
{
    const int f32 = *dtf;
    int idx = blockIdx.x * 256 + threadIdx.x;
    if (idx >= 2816) return;
    float v = 0.f;
    if (idx >= 2432)      v = ldin(b2, idx - 2432, f32);
    else if (idx >= 1920) v = ldin(b1, idx - 1920, f32);
    else if (idx >= 1536) v = ldin(bp, idx - 1536, f32);
    dst[idx] = f2b(v);
}

// ---------------------------------------------------------------------------
// Kernel 1: Time2Vec + concat -> h [NT, 384] bf16
// ---------------------------------------------------------------------------
__global__ void k_t2v(const void* __restrict__ x, const void* __restrict__ wb,
                      const void* __restrict__ bb, const void* __restrict__ wa,
                      const void* __restrict__ ba, bf16* __restrict__ h,
                      const int* __restrict__ dtf)
{
    const int f32 = *dtf;
    int row = blockIdx.x;
    int f = threadIdx.x;                 // 0..127
    float xv = ldin(x, (size_t)row * F_ + f, f32);
    float prod = xv * ldin(wa, f, f32);  // K=1
    #pragma unroll
    for (int off = 32; off; off >>= 1) prod += __shfl_down(prod, off, 64);
    __shared__ float sdot[2];
    if ((threadIdx.x & 63) == 0) sdot[threadIdx.x >> 6] = prod;
    __syncthreads();
    float dot = sdot[0] + sdot[1];

    float bias = ldin(wb, f, f32) * xv + ldin(bb, f, f32);
    float sn   = sinf(dot + ldin(ba, f, f32));
    bf16* hr = h + (size_t)row * D_;
    hr[f]            = f2b(xv);
    hr[F_ + 2*f]     = f2b(bias);
    hr[F_ + 2*f + 1] = f2b(sn);
}

// ---------------------------------------------------------------------------
// Kernel 2: MFMA GEMM  C[M x N] = A[M x K](bf16) * Wt[N x K]^T(bf16) + bias
// 128x128 tile, BK=64, block 256 (4 waves, each 64x64 quadrant of 16x16 tiles)
// mfma_f32_16x16x32_bf16 (layouts HW-validated in R4):
//   A-frag lane(r,g): A[m=r][k=g*8+j];  B-frag: B[k=g*8+j][n=r] = Wt[n=r][k..]
//   C/D lane(r,g) reg: D[row=4g+reg][col=r]
// qcols>0: scale cols<qcols by qscale (fused q/sqrt(HS) — here unused; scale
// is folded into the pack, kept for generality). BIAS/RELU compile-time.
// ---------------------------------------------------------------------------
template<bool BIAS, bool RELU>
__global__ __launch_bounds__(256) void
k_gemm_mfma(const bf16* __restrict__ A, const bf16* __restrict__ Wt,
            const bf16* __restrict__ bias, bf16* __restrict__ C,
            int K, int N)
{
    __shared__ __align__(16) bf16 As[128][72];   // +8 pad: 2-way max (free)
    __shared__ __align__(16) bf16 Bs[128][72];

    const int tid  = threadIdx.x;
    const int wave = tid >> 6;
    const int lane = tid & 63;
    const int r    = lane & 15;
    const int g    = lane >> 4;
    const int rh   = (wave & 1) * 64;     // row half
    const int chh  = (wave >> 1) * 64;    // col half
    const int row0 = blockIdx.x * 128;
    const int col0 = blockIdx.y * 128;

    floatx4 acc[4][4];
    #pragma unroll
    for (int mt = 0; mt < 4; mt++)
        #pragma unroll
        for (int nt = 0; nt < 4; nt++) acc[mt][nt] = (floatx4){0.f,0.f,0.f,0.f};

    for (int k0 = 0; k0 < K; k0 += 64) {
        #pragma unroll
        for (int s = 0; s < 4; s++) {
            int i = tid + s * 256;               // 0..1023
            int row = i >> 3, c8 = i & 7;
            *(uint4*)&As[row][c8 * 8] =
                *(const uint4*)(A + (size_t)(row0 + row) * K + k0 + c8 * 8);
            *(uint4*)&Bs[row][c8 * 8] =
                *(const uint4*)(Wt + (size_t)(col0 + row) * K + k0 + c8 * 8);
        }
        __syncthreads();
        #pragma unroll
        for (int ks = 0; ks < 2; ks++) {
            short8 af[4], bf[4];
            #pragma unroll
            for (int mt = 0; mt < 4; mt++)
                af[mt] = *(const short8*)&As[rh + mt * 16 + r][ks * 32 + g * 8];
            #pragma unroll
            for (int nt = 0; nt < 4; nt++)
                bf[nt] = *(const short8*)&Bs[chh + nt * 16 + r][ks * 32 + g * 8];
            #pragma unroll
            for (int mt = 0; mt < 4; mt++)
                #pragma unroll
                for (int nt = 0; nt < 4; nt++)
                    acc[mt][nt] = __builtin_amdgcn_mfma_f32_16x16x32_bf16(
                        af[mt], bf[nt], acc[mt][nt], 0, 0, 0);
        }
        __syncthreads();
    }

    #pragma unroll
    for (int mt = 0; mt < 4; mt++) {
        #pragma unroll
        for (int nt = 0; nt < 4; nt++) {
            int col = col0 + chh + nt * 16 + r;
            float bv = BIAS ? b2f(bias[col]) : 0.f;
            #pragma unroll
            for (int reg = 0; reg < 4; reg++) {
                int row = row0 + rh + mt * 16 + 4 * g + reg;
                float v = acc[mt][nt][reg] + bv;
                if (RELU) v = fmaxf(v, 0.f);
                C[(size_t)row * N + col] = f2b(v);
            }
        }
    }
}

// ---------------------------------------------------------------------------
// Kernel 3: MFMA flash attention, 4 heads/launch, q/k/v read from cqkv
// [8192 x 1536] (col = mat*512 + hh*128 + ch), rows = b*T + t.
// grid (T/64 = 32, B*4 = 16), block 256.
// ---------------------------------------------------------------------------
#define ATM 64      /* q rows per block */
#define ATN 64      /* kv per iteration */
__global__ __launch_bounds__(256) void
k_attn_mfma(const bf16* __restrict__ cqkv, bf16* __restrict__ mo, int round)
{
    __shared__ __align__(16) bf16 Qs[64][136];   // stride 136 bf16 (pad +8)
    __shared__ __align__(16) bf16 Ks[64][136];
    __shared__ __align__(16) bf16 Vt[128][72];   // transposed V, stride 72
    __shared__ __align__(16) float Sw[4][16][68];// per-wave S (reused as P bf16)

    const int tid  = threadIdx.x;
    const int wave = tid >> 6;
    const int lane = tid & 63;
    const int r    = lane & 15;
    const int g    = lane >> 4;

    const int by = blockIdx.y;
    const int hh = by >> 2, b = by & 3;
    const int t0 = blockIdx.x * ATM;
    const int head = round * 4 + hh;

    const bf16* qb = cqkv + ((size_t)(b * T_ + t0)) * QS_ + hh * 128;
    const bf16* kb = cqkv + ((size_t)(b * T_)) * QS_ + 512 + hh * 128;
    const bf16* vb = cqkv + ((size_t)(b * T_)) * QS_ + 1024 + hh * 128;

    // ---- stage Q (64 x 128) ----
    for (int i = tid; i < 1024; i += 256) {
        int row = i >> 4, c8 = i & 15;
        *(uint4*)&Qs[row][c8 * 8] =
            *(const uint4*)(qb + (size_t)row * QS_ + c8 * 8);
    }
    __syncthreads();

    // Q A-frags (loop-invariant): 4 k-steps of K-dim 128
    short8 qfrag[4];
    #pragma unroll
    for (int ks = 0; ks < 4; ks++)
        qfrag[ks] = *(const short8*)&Qs[wave * 16 + r][ks * 32 + g * 8];

    floatx4 O[8];
    #pragma unroll
    for (int dt = 0; dt < 8; dt++) O[dt] = (floatx4){0.f, 0.f, 0.f, 0.f};
    float m_run = -1e30f, l_run = 0.f;

    bf16* pbase = (bf16*)&Sw[wave][0][0];   // P view: row stride 136 bf16

    for (int m0 = 0; m0 < T_; m0 += ATN) {
        __syncthreads();                     // protect Ks/Vt from prior iter reads
        // ---- stage K tile (64 x 128) ----
        for (int i = tid; i < 1024; i += 256) {
            int row = i >> 4, c8 = i & 15;
            *(uint4*)&Ks[row][c8 * 8] =
                *(const uint4*)(kb + (size_t)(m0 + row) * QS_ + c8 * 8);
        }
        // ---- stage V transposed (kv 64 x d 128 -> Vt[d][kv]) ----
        for (int i = tid; i < 1024; i += 256) {
            int kv = i & 63, c8 = i >> 6;
            uint4 raw = *(const uint4*)(vb + (size_t)(m0 + kv) * QS_ + c8 * 8);
            const bf16* e = (const bf16*)&raw;
            #pragma unroll
            for (int j = 0; j < 8; j++) Vt[c8 * 8 + j][kv] = e[j];
        }
        __syncthreads();

        // ---- S = Q K^T (16 x 64 per wave) ----
        #pragma unroll
        for (int nt = 0; nt < 4; nt++) {
            floatx4 acc = (floatx4){0.f, 0.f, 0.f, 0.f};
            #pragma unroll
            for (int ks = 0; ks < 4; ks++) {
                short8 kf = *(const short8*)&Ks[nt * 16 + r][ks * 32 + g * 8];
                acc = __builtin_amdgcn_mfma_f32_16x16x32_bf16(qfrag[ks], kf, acc, 0, 0, 0);
            }
            #pragma unroll
            for (int reg = 0; reg < 4; reg++)
                Sw[wave][4 * g + reg][nt * 16 + r] = acc[reg];
        }
        asm volatile("s_waitcnt lgkmcnt(0)" ::: "memory");

        // ---- online softmax: lane owns row r, cols 16g..16g+15 ----
        float sv[16];
        #pragma unroll
        for (int q4i = 0; q4i < 4; q4i++) {
            float4 t = *(const float4*)&Sw[wave][r][16 * g + 4 * q4i];
            sv[4*q4i+0] = t.x; sv[4*q4i+1] = t.y; sv[4*q4i+2] = t.z; sv[4*q4i+3] = t.w;
        }
        float mx = m_run;
        #pragma unroll
        for (int j = 0; j < 16; j++) mx = fmaxf(mx, sv[j]);
        mx = fmaxf(mx, __shfl_xor(mx, 16));
        mx = fmaxf(mx, __shfl_xor(mx, 32));
        float cr = __expf(m_run - mx);
        float tsum = 0.f;
        #pragma unroll
        for (int j = 0; j < 16; j++) { sv[j] = __expf(sv[j] - mx); tsum += sv[j]; }
        tsum += __shfl_xor(tsum, 16);
        tsum += __shfl_xor(tsum, 32);
        l_run = l_run * cr + tsum;
        m_run = mx;

        // write P (bf16) over Sw: row r, k-cols 16g..16g+15
        short8 p0, p1;
        #pragma unroll
        for (int j = 0; j < 8; j++) {
            p0[j] = (short)f2bu(sv[j]);
            p1[j] = (short)f2bu(sv[8 + j]);
        }
        *(short8*)(pbase + r * 136 + 16 * g)     = p0;
        *(short8*)(pbase + r * 136 + 16 * g + 8) = p1;
        asm volatile("s_waitcnt lgkmcnt(0)" ::: "memory");

        // ---- rescale O by per-row cr ----
        float crg[4];
        #pragma unroll
        for (int reg = 0; reg < 4; reg++) crg[reg] = __shfl(cr, 4 * g + reg);
        #pragma unroll
        for (int dt = 0; dt < 8; dt++) {
            O[dt][0] *= crg[0]; O[dt][1] *= crg[1];
            O[dt][2] *= crg[2]; O[dt][3] *= crg[3];
        }

        // ---- O += P V ----
        short8 pf0 = *(const short8*)(pbase + r * 136 + 8 * g);
        short8 pf1 = *(const short8*)(pbase + r * 136 + 32 + 8 * g);
        #pragma unroll
        for (int dt = 0; dt < 8; dt++) {
            short8 vf0 = *(const short8*)&Vt[dt * 16 + r][8 * g];
            O[dt] = __builtin_amdgcn_mfma_f32_16x16x32_bf16(pf0, vf0, O[dt], 0, 0, 0);
            short8 vf1 = *(const short8*)&Vt[dt * 16 + r][32 + 8 * g];
            O[dt] = __builtin_amdgcn_mfma_f32_16x16x32_bf16(pf1, vf1, O[dt], 0, 0, 0);
        }
    }

    // ---- epilogue: O / l, write mo [B,T,H,HS] ----
    float linv[4];
    #pragma unroll
    for (int reg = 0; reg < 4; reg++) linv[reg] = 1.f / __shfl(l_run, 4 * g + reg);
    #pragma unroll
    for (int dt = 0; dt < 8; dt++) {
        #pragma unroll
        for (int reg = 0; reg < 4; reg++) {
            int t = t0 + wave * 16 + 4 * g + reg;
            mo[(((size_t)(b * T_ + t)) * H_ + head) * HS_ + dt * 16 + r] =
                f2b(O[dt][reg] * linv[reg]);
        }
    }
}

// ---------------------------------------------------------------------------
// Kernel 5: residual + LayerNorm. FINAL=true writes d_out (dtype per flag).
// Safe in-place (out==in1): all reads precede the reduction barriers.
// ---------------------------------------------------------------------------
template<bool FINAL>
__global__ void k_ln(const bf16* __restrict__ in1, const bf16* __restrict__ in2,
                     const void* __restrict__ g, const void* __restrict__ be,
                     void* __restrict__ out, const int* __restrict__ dtf)
{
    const int f32 = *dtf;
    int row = blockIdx.x;
    int tid = threadIdx.x;
    size_t base = (size_t)row * D_;
    int c0 = tid, c1 = tid + 128, c2 = tid + 256;
    float x0 = b2f(in1[base + c0]) + b2f(in2[base + c0]);
    float x1 = b2f(in1[base + c1]) + b2f(in2[base + c1]);
    float x2 = b2f(in1[base + c2]) + b2f(in2[base + c2]);

    __shared__ float sb1[2], sb2[2];
    float s = x0 + x1 + x2;
    #pragma unroll
    for (int off = 32; off; off >>= 1) s += __shfl_down(s, off, 64);
    if ((tid & 63) == 0) sb1[tid >> 6] = s;
    __syncthreads();
    float m = (sb1[0] + sb1[1]) * (1.f / D_);

    float d0 = x0 - m, d1 = x1 - m, d2 = x2 - m;
    float sq = d0*d0 + d1*d1 + d2*d2;
    #pragma unroll
    for (int off = 32; off; off >>= 1) sq += __shfl_down(sq, off, 64);
    if ((tid & 63) == 0) sb2[tid >> 6] = sq;
    __syncthreads();
    float rstd = rsqrtf((sb2[0] + sb2[1]) * (1.f / D_) + 1e-6f);

    float y0 = ldin(g, c0, f32) * d0 * rstd + ldin(be, c0, f32);
    float y1 = ldin(g, c1, f32) * d1 * rstd + ldin(be, c1, f32);
    float y2 = ldin(g, c2, f32) * d2 * rstd + ldin(be, c2, f32);
    if (FINAL && f32) {
        float* o = (float*)out;
        o[base + c0] = y0; o[base + c1] = y1; o[base + c2] = y2;
    } else {
        bf16* o = (bf16*)out;
        o[base + c0] = f2b(y0); o[base + c1] = f2b(y1); o[base + c2] = f2b(y2);
    }
}

// ---------------------------------------------------------------------------
// Workspace (bf16 elems), ~52.2 MB:
//   h     [3,145,728]   @ 0
//   cqkv  [12,582,912]  @  3,145,728   (8192 x 1536, reused per round)
//   mo    [8,388,608]   @ 15,728,640
//   wqkv  [1,179,648]   @ 24,117,248   (2 rounds x 1536 x 384)
//   wp    [393,216]     @ 25,296,896
//   w1    [196,608]     @ 25,690,112
//   w2    [196,608]     @ 25,886,720
//   biasp [2,816]       @ 26,083,328   (zeros | bp | b1 | b2)
//   flag  int           @ 26,086,144
// aliases after attention: a = cqkv, h1 = h (in-place),
//   f = cqkv + 3,145,728 (4.2M), f2 = cqkv + 7,340,032 (3.1M)  [all in cqkv]
// ---------------------------------------------------------------------------
extern "C" void kernel_launch(void* const* d_in, const int* in_sizes, int n_in,
                              void* d_out, int out_size, void* d_ws, size_t ws_size,
                              hipStream_t stream)
{
    const void* x     = d_in[0];
    const void* wb    = d_in[1];
    const void* bb    = d_in[2];
    const void* wa    = d_in[3];
    const void* ba    = d_in[4];
    const void* Wq    = d_in[5];
    const void* Wk    = d_in[6];
    const void* Wv    = d_in[7];
    const void* Wp    = d_in[8];
    const void* bp    = d_in[9];
    const void* ln1_g = d_in[10];
    const void* ln1_b = d_in[11];
    const void* W1    = d_in[12];
    const void* b1    = d_in[13];
    const void* W2    = d_in[14];
    const void* b2    = d_in[15];
    const void* ln2_g = d_in[16];
    const void* ln2_b = d_in[17];

    bf16* ws    = (bf16*)d_ws;
    bf16* h     = ws;
    bf16* cqkv  = h + 3145728;
    bf16* mo    = cqkv + 12582912;
    bf16* wqkv  = mo + 8388608;
    bf16* wp    = wqkv + 1179648;
    bf16* w1    = wp + 393216;
    bf16* w2    = w1 + 196608;
    bf16* biasp = w2 + 196608;
    int*  flag  = (int*)(biasp + 2816);

    bf16* a  = cqkv;
    bf16* h1 = h;
    bf16* f  = cqkv + 3145728;
    bf16* f2 = cqkv + 7340032;

    k_detect<<<1, 64, 0, stream>>>(x, flag);

    // weight/bias packs (dtype-adaptive -> transposed bf16)
    k_pack_qkv<<<4608, 256, 0, stream>>>(Wq, Wk, Wv, wqkv, flag);
    k_pack_wp <<<1536, 256, 0, stream>>>(Wp, wp, flag);
    k_pack_w1 <<< 768, 256, 0, stream>>>(W1, w1, flag);
    k_pack_w2 <<< 768, 256, 0, stream>>>(W2, w2, flag);
    k_pack_bias<<< 11, 256, 0, stream>>>(bp, b1, b2, biasp, flag);

    k_t2v<<<NT_, 128, 0, stream>>>(x, wb, bb, wa, ba, h, flag);

    for (int round = 0; round < 2; round++) {
        dim3 gq(NT_ / 128, QS_ / 128);
        k_gemm_mfma<false, false><<<gq, 256, 0, stream>>>(
            h, wqkv + (size_t)round * QS_ * D_, nullptr, cqkv, D_, QS_);
        dim3 gatt(T_ / ATM, B_ * 4);
        k_attn_mfma<<<gatt, 256, 0, stream>>>(cqkv, mo, round);
    }

    dim3 gp(NT_ / 128, D_ / 128);
    k_gemm_mfma<true, false><<<gp, 256, 0, stream>>>(
        mo, wp, biasp + 1536, a, H_ * HS_, D_);

    k_ln<false><<<NT_, 128, 0, stream>>>(h, a, ln1_g, ln1_b, h1, flag);

    dim3 g1(NT_ / 128, FF_ / 128);
    k_gemm_mfma<true, true><<<g1, 256, 0, stream>>>(
        h1, w1, biasp + 1920, f, D_, FF_);

    dim3 g2(NT_ / 128, D_ / 128);
    k_gemm_mfma<true, false><<<g2, 256, 0, stream>>>(
        f, w2, biasp + 2432, f2, FF_, D_);

    k_ln<true><<<NT_, 128, 0, stream>>>(h1, f2, ln2_g, ln2_b, d_out, flag);
}